// Round 1
// baseline (107.844 us; speedup 1.0000x reference)
//
#include <hip/hip_runtime.h>
#include <cstdint>
#include <cstddef>

// Problem constants (fixed by the reference: N=4096, D=512)
constexpr int N_ROWS = 4096;
constexpr int D      = 512;
constexpr int M      = 8192;   // 2N
constexpr int NTILE  = 64;     // M / 128 : partials chunk grid (128-row chunks)
constexpr int NJOB   = 1056;   // sum_{i<32} (64 - 2i) : 256x128 tile jobs
constexpr int BKB    = 64;     // K-bytes per K-tile (fp8, K=64)
constexpr int NKT    = D / BKB;          // 8 K-tiles
constexpr int ATB    = 256 * BKB;        // 16 KB A-tile bytes per K-tile
constexpr int BTB    = 128 * BKB;        // 8 KB  B-tile bytes per K-tile
constexpr int TILEB  = ATB + BTB;        // 24576 bytes per LDS buffer

using f32x4 = __attribute__((ext_vector_type(4))) float;
using ul2   = __attribute__((ext_vector_type(2))) unsigned long;

// 16B async global->LDS copy. LDS dest is wave-uniform base + lane*16.
#define ASYNC_CP16(gsrc, ldst)                                                      \
    __builtin_amdgcn_global_load_lds(                                               \
        (const __attribute__((address_space(1))) unsigned int*)(gsrc),              \
        (__attribute__((address_space(3))) unsigned int*)(ldst), 16, 0, 0)

// sum of squares of the 4 fp8 e4m3 bytes in `pk` (selector must be literal)
#define SS_FP8(pk, accum)                                                           \
    do {                                                                            \
        float f0 = __builtin_amdgcn_cvt_f32_fp8((pk), 0);                           \
        float f1 = __builtin_amdgcn_cvt_f32_fp8((pk), 1);                           \
        float f2 = __builtin_amdgcn_cvt_f32_fp8((pk), 2);                           \
        float f3 = __builtin_amdgcn_cvt_f32_fp8((pk), 3);                           \
        (accum) += f0 * f0 + f1 * f1 + f2 * f2 + f3 * f3;                           \
    } while (0)

// ---------------------------------------------------------------------------
// Kernel 1: fused normalize + fp8-quantize + positive-pair logits (unchanged).
// Z rows stored fp8 e4m3 with per-64B-block K-group permutation
// [0,4,1,5,2,6,3,7] so one ds_read_b128 yields both K-halves of two
// mfma_16x16x32_fp8 fragments.
// ---------------------------------------------------------------------------
__global__ __launch_bounds__(256) void normpos_kernel(
    const float* __restrict__ emb_i, const float* __restrict__ emb_j,
    uint8_t* __restrict__ zb, float* __restrict__ diagss,
    float* __restrict__ pos)
{
    const int wave = threadIdx.x >> 6, lane = threadIdx.x & 63;
    const int k = blockIdx.x * 4 + wave;

    const float4* a = (const float4*)(emb_i + (size_t)k * D);
    const float4* b = (const float4*)(emb_j + (size_t)k * D);
    float4 a0 = a[lane * 2], a1 = a[lane * 2 + 1];
    float4 b0 = b[lane * 2], b1 = b[lane * 2 + 1];

    float ssi = a0.x*a0.x + a0.y*a0.y + a0.z*a0.z + a0.w*a0.w
              + a1.x*a1.x + a1.y*a1.y + a1.z*a1.z + a1.w*a1.w;
    float ssj = b0.x*b0.x + b0.y*b0.y + b0.z*b0.z + b0.w*b0.w
              + b1.x*b1.x + b1.y*b1.y + b1.z*b1.z + b1.w*b1.w;
    float dp  = a0.x*b0.x + a0.y*b0.y + a0.z*b0.z + a0.w*b0.w
              + a1.x*b1.x + a1.y*b1.y + a1.z*b1.z + a1.w*b1.w;
    #pragma unroll
    for (int off = 32; off; off >>= 1) {
        ssi += __shfl_xor(ssi, off, 64);
        ssj += __shfl_xor(ssj, off, 64);
        dp  += __shfl_xor(dp,  off, 64);
    }
    const float invi = rsqrtf(ssi), invj = rsqrtf(ssj);

    const float zi[8] = {a0.x*invi, a0.y*invi, a0.z*invi, a0.w*invi,
                         a1.x*invi, a1.y*invi, a1.z*invi, a1.w*invi};
    const float zj[8] = {b0.x*invj, b0.y*invj, b0.z*invj, b0.w*invj,
                         b1.x*invj, b1.y*invj, b1.z*invj, b1.w*invj};

    int pi0 = __builtin_amdgcn_cvt_pk_fp8_f32(zi[0], zi[1], 0, false);
    pi0     = __builtin_amdgcn_cvt_pk_fp8_f32(zi[2], zi[3], pi0, true);
    int pi1 = __builtin_amdgcn_cvt_pk_fp8_f32(zi[4], zi[5], 0, false);
    pi1     = __builtin_amdgcn_cvt_pk_fp8_f32(zi[6], zi[7], pi1, true);
    int pj0 = __builtin_amdgcn_cvt_pk_fp8_f32(zj[0], zj[1], 0, false);
    pj0     = __builtin_amdgcn_cvt_pk_fp8_f32(zj[2], zj[3], pj0, true);
    int pj1 = __builtin_amdgcn_cvt_pk_fp8_f32(zj[4], zj[5], 0, false);
    pj1     = __builtin_amdgcn_cvt_pk_fp8_f32(zj[6], zj[7], pj1, true);

    float dssi = 0.f, dssj = 0.f;
    SS_FP8(pi0, dssi);
    SS_FP8(pi1, dssi);
    SS_FP8(pj0, dssj);
    SS_FP8(pj1, dssj);

    const int g = lane, bb = g >> 3, w = g & 7;
    const int sl = bb * 8 + ((w < 4) ? (w * 2) : ((w - 4) * 2 + 1));
    const unsigned long long vi =
        ((unsigned long long)(unsigned)pi1 << 32) | (unsigned)pi0;
    const unsigned long long vj =
        ((unsigned long long)(unsigned)pj1 << 32) | (unsigned)pj0;
    *(unsigned long long*)(zb + (size_t)k * D + sl * 8)            = vi;
    *(unsigned long long*)(zb + (size_t)(k + N_ROWS) * D + sl * 8) = vj;

    #pragma unroll
    for (int off = 32; off; off >>= 1) {
        dssi += __shfl_xor(dssi, off, 64);
        dssj += __shfl_xor(dssj, off, 64);
    }
    if (lane == 0) {
        diagss[k]          = dssi;
        diagss[k + N_ROWS] = dssj;
        pos[k]             = 2.0f * dp * invi * invj;
    }
}

// ---------------------------------------------------------------------------
// Kernel 2: symmetric fused sim-GEMM (fp8 e4m3), 8-phase-style schedule.
//
// 256x128 output tiles. Jobs: (i, j) with i in [0,32) (256-row band),
// j in [2i, 64) (128-col band) -> 1056 jobs (82.5% packing on 256 CUs vs
// 68.8% for 528x 256^2 jobs). Tiles with j in {2i, 2i+1} straddle the
// diagonal ("diag-class"): rows-only contributions (each element of the
// diagonal 256-block counted exactly once via rows). Strictly-upper tiles
// (j >= 2i+2) contribute rows AND mirrored cols split per 128-row half.
// Coverage of partials[rc][cc] (exactly once each):
//   cc >= 2i  : rows of tile (i=rc>>1, cc)
//   cc <  2i  : cols of tile (cc>>1, rc)   [strictly-upper since rc >= 2i]
//
// Schedule (T3+T4+T5): 8 waves (4 row-groups x 2 col-groups, 64x64 out each,
// acc 4x4 f32x4 = 64 VGPR), BK=64 B, THREE 24 KB LDS buffers so the K-tile
// boundary wait is a counted vmcnt(3) (kt+1 landed, kt+2 in flight) --
// never a full drain in the main loop. Per K-tile: 2 phases of 16 MFMA,
// each {ds_read -> raw s_barrier -> lgkmcnt(0)+sched_barrier -> setprio(1)
// MFMA setprio(0) -> s_barrier}. Stage loads for kt+2 issue in phase 0
// (buffer (kt+2)%3 = (kt-1)%3, whose reads completed before kt's opening
// barrier). XOR chunk-swizzle on stage-source + read keeps ds_read_b128
// conflict-free (same scheme as the verified 128^2 kernel).
// LDS: 3*24576 + rp/cp 4 KB = 76 KB -> 2 blocks/CU; launch_bounds(512,4)
// caps VGPR at 128 for 16 waves/CU.
// ---------------------------------------------------------------------------
#define MM2(AC, AF, BF)                                                             \
    do {                                                                            \
        AC = __builtin_amdgcn_mfma_f32_16x16x32_fp8_fp8(                            \
                 (long)(AF)[0], (long)(BF)[0], AC, 0, 0, 0);                        \
        AC = __builtin_amdgcn_mfma_f32_16x16x32_fp8_fp8(                            \
                 (long)(AF)[1], (long)(BF)[1], AC, 0, 0, 0);                        \
    } while (0)

__global__ __launch_bounds__(512, 4) void simgemm_kernel(
    const uint8_t* __restrict__ zb, float* __restrict__ partials)
{
    __shared__ ul2 ldsV[3 * TILEB / 16];   // 72 KB, 3 K-tile buffers
    __shared__ float rp[8][64];            // per-wave row partials
    __shared__ float cp[8][64];            // per-wave col partials
    uint8_t* lds = (uint8_t*)ldsV;

    const int tid  = threadIdx.x;
    const int wave = tid >> 6, lane = tid & 63;
    const int l15  = lane & 15, ks = lane >> 4;

    // Decode job t -> (i, j).  C(i) = i*(65-i) jobs before band i.
    const int t = blockIdx.x;
    int i = (int)((65.0f - sqrtf(4225.0f - 4.0f * (float)t)) * 0.5f);
    if (i < 0) i = 0;
    if (i > 31) i = 31;
    while (i > 0 && i * (65 - i) > t) --i;
    while ((i + 1) * (65 - (i + 1)) <= t) ++i;
    const int j = 2 * i + (t - i * (65 - i));
    const bool diagcls = (j - 2 * i) < 2;

    // Staging: thread tid covers LDS byte range tid*16 of each 8 KB region
    // (global_load_lds writes base + lane*16, wave base = wave*1024).
    // row = tid>>2 (128 rows per instr), phys chunk = tid&3, source chunk
    // XOR-swizzled by (row>>1)&3 (matches read-side swizzle below).
    const int srow = tid >> 2;
    const int sch  = (tid & 3) ^ ((srow >> 1) & 3);
    const uint8_t* gA = zb + (size_t)(i * 256 + srow) * D + sch * 16;
    const uint8_t* gB = zb + (size_t)(j * 128 + srow) * D + sch * 16;
    uint8_t* lw = lds + wave * 1024;

    // 3 global_load_lds per wave per K-tile: A rows [0,128), A rows [128,256), B.
#define STAGE(KT, BUF)                                                              \
    do {                                                                            \
        const uint8_t* _a = gA + (KT) * BKB;                                        \
        const uint8_t* _b = gB + (KT) * BKB;                                        \
        uint8_t* _l = lw + (BUF) * TILEB;                                           \
        ASYNC_CP16(_a,           _l);                                               \
        ASYNC_CP16(_a + 128 * D, _l + 8192);                                        \
        ASYNC_CP16(_b,           _l + ATB);                                         \
    } while (0)

    // Fragment read offsets. wave = wr*2 + wc: wr row-group (64 rows),
    // wc col-group (64 cols). swb = XOR-swizzled 16B chunk (conflict-free).
    const int wr  = wave >> 1, wc = wave & 1;
    const int swb = (ks ^ ((l15 >> 1) & 3)) * 16;
    const int aof = (wr * 64 + l15) * BKB + swb;          // + fi*1024
    const int bof = ATB + (wc * 64 + l15) * BKB + swb;    // + fj*1024

    f32x4 acc[4][4] = {};

    // Prologue: stage kt0, kt1; wait kt0 (kt1 stays in flight); barrier.
    STAGE(0, 0);
    STAGE(1, 1);
    asm volatile("s_waitcnt vmcnt(3)" ::: "memory");
    __builtin_amdgcn_s_barrier();

    #pragma unroll
    for (int kt = 0; kt < NKT; ++kt) {
        const uint8_t* La = lds + (kt % 3) * TILEB;

        // ---- phase 0: A-frags 0,1 + all B-frags; stage kt+2 ----
        ul2 a0 = *(const ul2*)(La + aof);
        ul2 a1 = *(const ul2*)(La + aof + 1024);
        ul2 b0 = *(const ul2*)(La + bof);
        ul2 b1 = *(const ul2*)(La + bof + 1024);
        ul2 b2 = *(const ul2*)(La + bof + 2048);
        ul2 b3 = *(const ul2*)(La + bof + 3072);
        if (kt + 2 < NKT) STAGE(kt + 2, (kt + 2) % 3);
        __builtin_amdgcn_s_barrier();
        asm volatile("s_waitcnt lgkmcnt(0)" ::: "memory");
        __builtin_amdgcn_sched_barrier(0);
        __builtin_amdgcn_s_setprio(1);
        MM2(acc[0][0], a0, b0); MM2(acc[0][1], a0, b1);
        MM2(acc[0][2], a0, b2); MM2(acc[0][3], a0, b3);
        MM2(acc[1][0], a1, b0); MM2(acc[1][1], a1, b1);
        MM2(acc[1][2], a1, b2); MM2(acc[1][3], a1, b3);
        __builtin_amdgcn_s_setprio(0);
        __builtin_amdgcn_s_barrier();

        // ---- phase 1: A-frags 2,3 ----
        ul2 a2 = *(const ul2*)(La + aof + 2048);
        ul2 a3 = *(const ul2*)(La + aof + 3072);
        __builtin_amdgcn_s_barrier();
        asm volatile("s_waitcnt lgkmcnt(0)" ::: "memory");
        __builtin_amdgcn_sched_barrier(0);
        __builtin_amdgcn_s_setprio(1);
        MM2(acc[2][0], a2, b0); MM2(acc[2][1], a2, b1);
        MM2(acc[2][2], a2, b2); MM2(acc[2][3], a2, b3);
        MM2(acc[3][0], a3, b0); MM2(acc[3][1], a3, b1);
        MM2(acc[3][2], a3, b2); MM2(acc[3][3], a3, b3);
        __builtin_amdgcn_s_setprio(0);
        // K-tile boundary: ensure kt+1 staged. Outstanding = kt+1 (3) +
        // kt+2 (3, if issued) -> counted vmcnt(3); full drain only at the
        // pipeline tail.
        if (kt < NKT - 2) {
            asm volatile("s_waitcnt vmcnt(3)" ::: "memory");
        } else if (kt == NKT - 2) {
            asm volatile("s_waitcnt vmcnt(0)" ::: "memory");
        }
        __builtin_amdgcn_s_barrier();
    }

    // Epilogue. C/D: row = ks*4+r, col = l15 within each 16x16.
    // e = exp(sim/T) = exp(2*acc).
    float rowp[4][4] = {};
    #pragma unroll
    for (int jj = 0; jj < 4; ++jj) {
        float cpj = 0.f;
        #pragma unroll
        for (int ii = 0; ii < 4; ++ii)
            #pragma unroll
            for (int r = 0; r < 4; ++r) {
                float e = __expf(2.0f * acc[ii][jj][r]);
                rowp[ii][r] += e;
                cpj += e;
            }
        if (!diagcls) {   // col partial over this wave's 64 rows
            cpj += __shfl_xor(cpj, 16, 64);
            cpj += __shfl_xor(cpj, 32, 64);
            if (ks == 0) cp[wave][jj * 16 + l15] = cpj;
        }
    }
    #pragma unroll
    for (int ii = 0; ii < 4; ++ii)
        #pragma unroll
        for (int r = 0; r < 4; ++r) {
            float e = rowp[ii][r];
            e += __shfl_xor(e, 1, 64);
            e += __shfl_xor(e, 2, 64);
            e += __shfl_xor(e, 4, 64);
            e += __shfl_xor(e, 8, 64);
            if (l15 == 0) rp[wave][ii * 16 + ks * 4 + r] = e;
        }
    __syncthreads();

    // Rows: tile row = tid (0..255). Combine the two waves (wc=0,1) sharing
    // each row-group. Dest chunk rc = 2i + (tid>>7), col-chunk j.
    if (tid < 256) {
        const int rl = tid & 63;
        const float v = rp[(tid >> 6) * 2][rl] + rp[(tid >> 6) * 2 + 1][rl];
        const int rc = 2 * i + (tid >> 7);
        partials[((size_t)rc * NTILE + j) * 128 + (tid & 127)] = v;
    } else if (!diagcls) {
        // Cols (mirror): c2 = tid-256: half = row-half of tile, c = tile col.
        // Combine waves (wr in {0,1} or {2,3}) x matching wc.
        const int c2 = tid - 256;
        const int half = c2 >> 7, c = c2 & 127;
        const int wcc = c >> 6, cl = c & 63;
        const float v = cp[half * 4 + wcc][cl] + cp[half * 4 + 2 + wcc][cl];
        partials[((size_t)j * NTILE + 2 * i + half) * 128 + c] = v;
    }
}

// ---------------------------------------------------------------------------
// Kernel 3: per-tile-row reduction of partials + log terms + pos chunk.
// ---------------------------------------------------------------------------
__global__ __launch_bounds__(256) void rowfin_kernel(
    const float* __restrict__ partials, const float* __restrict__ diagss,
    const float* __restrict__ pos, float* __restrict__ lgpart)
{
    const int r  = blockIdx.x;          // tile-row 0..63
    const int ri = threadIdx.x & 127;   // row within tile
    const int ch = threadIdx.x >> 7;    // c-half 0/1
    const float* base = partials + (size_t)r * NTILE * 128 + ri;
    float s = 0.f;
    #pragma unroll
    for (int c = 0; c < 32; ++c)
        s += base[(size_t)(ch * 32 + c) * 128];
    __shared__ float half1[128];
    __shared__ float red[4];
    if (ch == 1) half1[ri] = s;
    __syncthreads();
    float lg = 0.f;
    if (ch == 0) {
        float rs = s + half1[ri];
        int row = r * 128 + ri;
        lg = __logf(rs - __expf(2.0f * diagss[row]));
    }
    if (threadIdx.x < 64)
        lg -= 2.0f * pos[r * 64 + threadIdx.x];
    #pragma unroll
    for (int off = 32; off; off >>= 1) lg += __shfl_xor(lg, off, 64);
    const int wave = threadIdx.x >> 6, lane = threadIdx.x & 63;
    if (lane == 0) red[wave] = lg;
    __syncthreads();
    if (threadIdx.x == 0) lgpart[r] = red[0] + red[1] + red[2] + red[3];
}

// ---------------------------------------------------------------------------
// Kernel 4: loss = sum_r lgpart[r] / 8192   (one wave)
// ---------------------------------------------------------------------------
__global__ __launch_bounds__(64) void loss_kernel(
    const float* __restrict__ lgpart, float* __restrict__ out)
{
    float local = lgpart[threadIdx.x];
    #pragma unroll
    for (int off = 32; off; off >>= 1) local += __shfl_xor(local, off, 64);
    if (threadIdx.x == 0) out[0] = local * (1.0f / 8192.0f);
}

// ---------------------------------------------------------------------------
extern "C" void kernel_launch(void* const* d_in, const int* in_sizes, int n_in,
                              void* d_out, int out_size, void* d_ws, size_t ws_size,
                              hipStream_t stream)
{
    const float* emb_i = (const float*)d_in[0];
    const float* emb_j = (const float*)d_in[1];

    // ws layout: zb fp8 [M][D] (4 MB) | partials f32[64][64][128] (2 MB)
    //            | diagss f32[M] | pos f32[N] | lgpart f32[64]  (~6.05 MB)
    uint8_t* zb = (uint8_t*)d_ws;
    float* partials = (float*)((char*)d_ws + (size_t)M * D);
    float* diagss   = partials + (size_t)NTILE * NTILE * 128;
    float* pos      = diagss + M;
    float* lgpart   = pos + N_ROWS;
    float* out      = (float*)d_out;

    normpos_kernel<<<N_ROWS / 4, 256, 0, stream>>>(emb_i, emb_j, zb, diagss, pos);
    simgemm_kernel<<<NJOB, 512, 0, stream>>>(zb, partials);
    rowfin_kernel<<<NTILE, 256, 0, stream>>>(partials, diagss, pos, lgpart);
    loss_kernel<<<1, 64, 0, stream>>>(lgpart, out);
}